// Round 1
// baseline (350.242 us; speedup 1.0000x reference)
//
#include <hip/hip_runtime.h>
#include <hip/hip_bf16.h>
#include <math.h>
#include <float.h>

#define N_NODES 10000
#define M_PTS   20000
#define E_EDGES 160000
#define C_CH    128
#define F_CH    128
#define NPB     8      // nodes per block in conv kernel
#define TPT     8      // threads per target in knn kernel
#define TGT_PER_BLK 32 // 256 threads / 8
#define TILE    2048   // knn source tile in LDS

// ---------- kernel 1: count edges per dst ----------
__global__ void count_kernel(const int* __restrict__ ei, int* __restrict__ cnt) {
    int e = blockIdx.x * blockDim.x + threadIdx.x;
    if (e < E_EDGES) {
        int dst = ei[E_EDGES + e];
        atomicAdd(&cnt[dst], 1);
    }
}

// ---------- kernel 2: exclusive scan over counts (single block) ----------
__global__ __launch_bounds__(1024) void scan_kernel(const int* __restrict__ cnt,
                                                    int* __restrict__ rowstart,
                                                    int* __restrict__ cursor) {
    __shared__ int part[1024];
    const int CH = 10; // 1024*10 >= 10000
    int t = threadIdx.x;
    int base = t * CH;
    int local[CH];
    int s = 0;
    for (int k = 0; k < CH; k++) {
        int idx = base + k;
        int v = (idx < N_NODES) ? cnt[idx] : 0;
        local[k] = s;
        s += v;
    }
    part[t] = s;
    __syncthreads();
    for (int off = 1; off < 1024; off <<= 1) {
        int v = (t >= off) ? part[t - off] : 0;
        __syncthreads();
        part[t] += v;
        __syncthreads();
    }
    int offset = (t > 0) ? part[t - 1] : 0;
    for (int k = 0; k < CH; k++) {
        int idx = base + k;
        if (idx < N_NODES) {
            int rs = offset + local[k];
            rowstart[idx] = rs;
            cursor[idx] = rs;
        }
    }
    if (t == 1023) rowstart[N_NODES] = part[1023];
}

// ---------- kernel 3: scatter edges into CSR + per-edge dx,dy ----------
__global__ void scatter_kernel(const int* __restrict__ ei, const float* __restrict__ pos,
                               int* __restrict__ cursor, int* __restrict__ esrc,
                               float* __restrict__ edx, float* __restrict__ edy) {
    int e = blockIdx.x * blockDim.x + threadIdx.x;
    if (e >= E_EDGES) return;
    int src = ei[e];
    int dst = ei[E_EDGES + e];
    float dxv = pos[2*dst]     - pos[2*src];
    float dyv = pos[2*dst + 1] - pos[2*src + 1];
    float r2 = dxv*dxv + dyv*dyv;
    float scale = 1.0f / (r2 + 0.01f);
    int p = atomicAdd(&cursor[dst], 1);
    esrc[p] = src;
    edx[p] = dxv * scale;
    edy[p] = dyv * scale;
}

// ---------- kernel 4: aggregate + W_conv matvec + ELU + W2 matvec + ELU ----------
__global__ __launch_bounds__(128) void conv_kernel(const float* __restrict__ x,
    const int* __restrict__ rowstart, const int* __restrict__ esrc,
    const float* __restrict__ edx, const float* __restrict__ edy,
    const float* __restrict__ Wc, const float* __restrict__ bc,
    const float* __restrict__ W2, const float* __restrict__ b2,
    float* __restrict__ h2out)
{
    __shared__ float sIn[NPB][4*C_CH]; // [agg_dx | agg_dy | agg_j | x]
    __shared__ float sH[NPB][F_CH];
    int f = threadIdx.x;
    int nodeBase = blockIdx.x * NPB;

    // phase 1: per-node aggregation (thread f owns channel f)
    for (int n = 0; n < NPB; n++) {
        int i = nodeBase + n;
        float xi = x[i*C_CH + f];
        int p0 = rowstart[i], p1 = rowstart[i+1];
        float a1 = 0.f, a2 = 0.f, a3 = 0.f;
        for (int p = p0; p < p1; p++) {
            int s = esrc[p];
            float dxe = edx[p], dye = edy[p];
            float xj = x[s*C_CH + f];
            float d = xi - xj;
            a1 = fmaf(d, dxe, a1);
            a2 = fmaf(d, dye, a2);
            a3 += xj;
        }
        float inv = 1.0f / fmaxf((float)(p1 - p0), 1.0f);
        sIn[n][f]          = a1 * inv;
        sIn[n][C_CH + f]   = a2 * inv;
        sIn[n][2*C_CH + f] = a3 * inv;
        sIn[n][3*C_CH + f] = xi;
    }
    __syncthreads();

    // phase 2: h1 = elu(concat(agg,x) @ Wc + bc)
    float acc[NPB];
    #pragma unroll
    for (int n = 0; n < NPB; n++) acc[n] = bc[f];
    #pragma unroll 4
    for (int k = 0; k < 4*C_CH; k++) {
        float w = Wc[k*F_CH + f];
        #pragma unroll
        for (int n = 0; n < NPB; n++) acc[n] = fmaf(sIn[n][k], w, acc[n]);
    }
    for (int n = 0; n < NPB; n++) {
        float v = acc[n];
        sH[n][f] = (v > 0.f) ? v : expm1f(v);
    }
    __syncthreads();

    // phase 3: h2 = elu(h1 @ W2 + b2)
    #pragma unroll
    for (int n = 0; n < NPB; n++) acc[n] = b2[f];
    #pragma unroll 4
    for (int k = 0; k < F_CH; k++) {
        float w = W2[k*F_CH + f];
        #pragma unroll
        for (int n = 0; n < NPB; n++) acc[n] = fmaf(sH[n][k], w, acc[n]);
    }
    for (int n = 0; n < NPB; n++) {
        float v = acc[n];
        v = (v > 0.f) ? v : expm1f(v);
        h2out[(nodeBase + n)*F_CH + f] = v;
    }
}

// ---------- kernel 5: brute-force 3-NN, 8 threads/target ----------
__global__ __launch_bounds__(256) void knn_kernel(const float* __restrict__ pos,
                                                  const float* __restrict__ pos_skip,
                                                  int* __restrict__ knn_idx,
                                                  float* __restrict__ knn_w) {
    __shared__ float stile[TILE*2];
    __shared__ float md[256*3];
    __shared__ int   mi[256*3];
    int tid = threadIdx.x;
    int sub = tid & (TPT-1);
    int t_local = tid >> 3;
    int tgt = blockIdx.x * TGT_PER_BLK + t_local;
    float tx = pos_skip[2*tgt];
    float ty = pos_skip[2*tgt + 1];

    float d0 = FLT_MAX, d1 = FLT_MAX, d2v = FLT_MAX;
    int   i0 = 0, i1 = 0, i2 = 0;

    for (int cb = 0; cb < N_NODES; cb += TILE) {
        int cnt = min(TILE, N_NODES - cb);
        __syncthreads();
        for (int j = tid; j < cnt; j += 256) {
            float2 p = ((const float2*)pos)[cb + j];
            stile[2*j]   = p.x;
            stile[2*j+1] = p.y;
        }
        __syncthreads();
        for (int j = sub; j < cnt; j += TPT) {
            float sx = stile[2*j], sy = stile[2*j+1];
            float ddx = sx - tx;
            float ddy = sy - ty;
            // match numpy: dx*dx + dy*dy, no fused contraction
            float dd = __fadd_rn(__fmul_rn(ddx, ddx), __fmul_rn(ddy, ddy));
            int gj = cb + j;
            bool lt2 = dd < d2v;
            bool lt1 = dd < d1;
            bool lt0 = dd < d0;
            d2v = lt1 ? d1 : (lt2 ? dd : d2v);
            i2  = lt1 ? i1 : (lt2 ? gj : i2);
            d1  = lt0 ? d0 : (lt1 ? dd : d1);
            i1  = lt0 ? i0 : (lt1 ? gj : i1);
            d0  = lt0 ? dd : d0;
            i0  = lt0 ? gj : i0;
        }
    }
    md[tid*3+0] = d0;  md[tid*3+1] = d1;  md[tid*3+2] = d2v;
    mi[tid*3+0] = i0;  mi[tid*3+1] = i1;  mi[tid*3+2] = i2;
    __syncthreads();

    if (sub == 0) {
        int base = (t_local*TPT)*3;
        float bd_[3]; int bi_[3];
        for (int k = 0; k < 3; k++) {
            float bd = FLT_MAX; int bidx = 0x7fffffff; int bslot = 0;
            for (int c = 0; c < TPT*3; c++) {
                float dc = md[base+c]; int ic = mi[base+c];
                if (dc < bd || (dc == bd && ic < bidx)) { bd = dc; bidx = ic; bslot = c; }
            }
            md[base+bslot] = FLT_MAX;
            bd_[k] = bd; bi_[k] = bidx;
        }
        float w0 = 1.0f / fmaxf(bd_[0], 1e-16f);
        float w1 = 1.0f / fmaxf(bd_[1], 1e-16f);
        float w2 = 1.0f / fmaxf(bd_[2], 1e-16f);
        float wsum = w0 + w1 + w2;
        knn_idx[tgt*3+0] = bi_[0];
        knn_idx[tgt*3+1] = bi_[1];
        knn_idx[tgt*3+2] = bi_[2];
        knn_w[tgt*3+0] = w0 / wsum;
        knn_w[tgt*3+1] = w1 / wsum;
        knn_w[tgt*3+2] = w2 / wsum;
    }
}

// ---------- kernel 6: weighted gather ----------
__global__ __launch_bounds__(128) void gather_kernel(const float* __restrict__ h2,
    const int* __restrict__ knn_idx, const float* __restrict__ knn_w,
    float* __restrict__ out)
{
    int m = blockIdx.x;
    int f = threadIdx.x;
    int j0 = knn_idx[m*3+0], j1 = knn_idx[m*3+1], j2 = knn_idx[m*3+2];
    float w0 = knn_w[m*3+0], w1 = knn_w[m*3+1], w2 = knn_w[m*3+2];
    float v = w0*h2[j0*F_CH+f] + w1*h2[j1*F_CH+f] + w2*h2[j2*F_CH+f];
    out[m*F_CH + f] = v;
}

extern "C" void kernel_launch(void* const* d_in, const int* in_sizes, int n_in,
                              void* d_out, int out_size, void* d_ws, size_t ws_size,
                              hipStream_t stream) {
    const float* x        = (const float*)d_in[0];
    const float* pos      = (const float*)d_in[1];
    const float* pos_skip = (const float*)d_in[2];
    const int*   ei       = (const int*)  d_in[3];
    const float* Wc       = (const float*)d_in[4];
    const float* bc       = (const float*)d_in[5];
    const float* W2       = (const float*)d_in[6];
    const float* b2       = (const float*)d_in[7];
    float* out = (float*)d_out;

    char* ws = (char*)d_ws;
    size_t off = 0;
    auto alloc = [&](size_t bytes) {
        void* p = ws + off;
        off = (off + bytes + 255) & ~(size_t)255;
        return p;
    };
    int*   cnt      = (int*)  alloc((size_t)N_NODES * 4);
    int*   cursor   = (int*)  alloc((size_t)N_NODES * 4);
    int*   rowstart = (int*)  alloc((size_t)(N_NODES + 1) * 4);
    int*   esrc     = (int*)  alloc((size_t)E_EDGES * 4);
    float* edx      = (float*)alloc((size_t)E_EDGES * 4);
    float* edy      = (float*)alloc((size_t)E_EDGES * 4);
    float* h2       = (float*)alloc((size_t)N_NODES * F_CH * 4);
    int*   knn_idx  = (int*)  alloc((size_t)M_PTS * 3 * 4);
    float* knn_w    = (float*)alloc((size_t)M_PTS * 3 * 4);

    hipMemsetAsync(cnt, 0, (size_t)N_NODES * 4, stream);
    count_kernel<<<(E_EDGES + 255) / 256, 256, 0, stream>>>(ei, cnt);
    scan_kernel<<<1, 1024, 0, stream>>>(cnt, rowstart, cursor);
    scatter_kernel<<<(E_EDGES + 255) / 256, 256, 0, stream>>>(ei, pos, cursor, esrc, edx, edy);
    conv_kernel<<<N_NODES / NPB, 128, 0, stream>>>(x, rowstart, esrc, edx, edy, Wc, bc, W2, b2, h2);
    knn_kernel<<<M_PTS / TGT_PER_BLK, 256, 0, stream>>>(pos, pos_skip, knn_idx, knn_w);
    gather_kernel<<<M_PTS, 128, 0, stream>>>(h2, knn_idx, knn_w, out);
}

// Round 2
// 236.736 us; speedup vs baseline: 1.4795x; 1.4795x over previous
//
#include <hip/hip_runtime.h>
#include <hip/hip_bf16.h>
#include <math.h>
#include <float.h>
#include <stdint.h>

#define N_NODES 10000
#define M_PTS   20000
#define E_EDGES 160000
#define C_CH    128
#define F_CH    128
#define NPB     8      // nodes per block in conv kernel
#define G_GRID  64     // knn grid resolution (64x64 cells, ~2.4 pts/cell)
#define N_CELLS (G_GRID*G_GRID)

// ---------- kernel 1: count edges per dst AND points per grid cell ----------
__global__ void count_all_kernel(const int* __restrict__ ei, const float* __restrict__ pos,
                                 int* __restrict__ cnt, int* __restrict__ cellcnt) {
    int i = blockIdx.x * blockDim.x + threadIdx.x;
    if (i < E_EDGES) {
        atomicAdd(&cnt[ei[E_EDGES + i]], 1);
    } else if (i < E_EDGES + N_NODES) {
        int j = i - E_EDGES;
        float px = pos[2*j], py = pos[2*j+1];
        int cx = min(max((int)(px * G_GRID), 0), G_GRID - 1);
        int cy = min(max((int)(py * G_GRID), 0), G_GRID - 1);
        atomicAdd(&cellcnt[cy * G_GRID + cx], 1);
    }
}

// ---------- kernel 2: exclusive scans (block 0: edges-per-dst, block 1: cells) ----------
__global__ __launch_bounds__(1024) void scan_both_kernel(
    const int* __restrict__ cnt, int* __restrict__ rowstart, int* __restrict__ cursor,
    const int* __restrict__ cellcnt, int* __restrict__ cellstart, int* __restrict__ cellcursor) {
    __shared__ int part[1024];
    int t = threadIdx.x;
    const int n    = (blockIdx.x == 0) ? N_NODES : N_CELLS;
    const int CH   = (blockIdx.x == 0) ? 10 : 4;
    const int* in  = (blockIdx.x == 0) ? cnt : cellcnt;
    int* outs      = (blockIdx.x == 0) ? rowstart : cellstart;
    int* outc      = (blockIdx.x == 0) ? cursor : cellcursor;

    int base = t * CH;
    int local[10];
    int s = 0;
    for (int k = 0; k < CH; k++) {
        int idx = base + k;
        int v = (idx < n) ? in[idx] : 0;
        local[k] = s;
        s += v;
    }
    part[t] = s;
    __syncthreads();
    for (int off = 1; off < 1024; off <<= 1) {
        int v = (t >= off) ? part[t - off] : 0;
        __syncthreads();
        part[t] += v;
        __syncthreads();
    }
    int offset = (t > 0) ? part[t - 1] : 0;
    for (int k = 0; k < CH; k++) {
        int idx = base + k;
        if (idx < n) {
            int rs = offset + local[k];
            outs[idx] = rs;
            outc[idx] = rs;
        }
    }
    if (t == 1023) outs[n] = part[1023];
}

// ---------- kernel 3: scatter edges into CSR + per-edge dx,dy; scatter points into cells ----------
__global__ void scatter_all_kernel(const int* __restrict__ ei, const float* __restrict__ pos,
                                   int* __restrict__ cursor, int* __restrict__ esrc,
                                   float* __restrict__ edx, float* __restrict__ edy,
                                   int* __restrict__ cellcursor, float2* __restrict__ spos,
                                   int* __restrict__ sidx) {
    int i = blockIdx.x * blockDim.x + threadIdx.x;
    if (i < E_EDGES) {
        int src = ei[i];
        int dst = ei[E_EDGES + i];
        float dxv = pos[2*dst]     - pos[2*src];
        float dyv = pos[2*dst + 1] - pos[2*src + 1];
        float r2 = dxv*dxv + dyv*dyv;
        float scale = 1.0f / (r2 + 0.01f);
        int p = atomicAdd(&cursor[dst], 1);
        esrc[p] = src;
        edx[p] = dxv * scale;
        edy[p] = dyv * scale;
    } else if (i < E_EDGES + N_NODES) {
        int j = i - E_EDGES;
        float px = pos[2*j], py = pos[2*j+1];
        int cx = min(max((int)(px * G_GRID), 0), G_GRID - 1);
        int cy = min(max((int)(py * G_GRID), 0), G_GRID - 1);
        int p = atomicAdd(&cellcursor[cy * G_GRID + cx], 1);
        spos[p] = make_float2(px, py);
        sidx[p] = j;
    }
}

// ---------- kernel 4: aggregate + W_conv matvec + ELU + W2 matvec + ELU ----------
__global__ __launch_bounds__(128) void conv_kernel(const float* __restrict__ x,
    const int* __restrict__ rowstart, const int* __restrict__ esrc,
    const float* __restrict__ edx, const float* __restrict__ edy,
    const float* __restrict__ Wc, const float* __restrict__ bc,
    const float* __restrict__ W2, const float* __restrict__ b2,
    float* __restrict__ h2out)
{
    __shared__ float sIn[NPB][4*C_CH]; // [agg_dx | agg_dy | agg_j | x]
    __shared__ float sH[NPB][F_CH];
    int f = threadIdx.x;
    int nodeBase = blockIdx.x * NPB;

    // phase 1: per-node aggregation (thread f owns channel f)
    for (int n = 0; n < NPB; n++) {
        int i = nodeBase + n;
        float xi = x[i*C_CH + f];
        int p0 = rowstart[i], p1 = rowstart[i+1];
        float a1 = 0.f, a2 = 0.f, a3 = 0.f;
        for (int p = p0; p < p1; p++) {
            int s = esrc[p];
            float dxe = edx[p], dye = edy[p];
            float xj = x[s*C_CH + f];
            float d = xi - xj;
            a1 = fmaf(d, dxe, a1);
            a2 = fmaf(d, dye, a2);
            a3 += xj;
        }
        float inv = 1.0f / fmaxf((float)(p1 - p0), 1.0f);
        sIn[n][f]          = a1 * inv;
        sIn[n][C_CH + f]   = a2 * inv;
        sIn[n][2*C_CH + f] = a3 * inv;
        sIn[n][3*C_CH + f] = xi;
    }
    __syncthreads();

    // phase 2: h1 = elu(concat(agg,x) @ Wc + bc)
    float acc[NPB];
    #pragma unroll
    for (int n = 0; n < NPB; n++) acc[n] = bc[f];
    #pragma unroll 4
    for (int k = 0; k < 4*C_CH; k++) {
        float w = Wc[k*F_CH + f];
        #pragma unroll
        for (int n = 0; n < NPB; n++) acc[n] = fmaf(sIn[n][k], w, acc[n]);
    }
    for (int n = 0; n < NPB; n++) {
        float v = acc[n];
        sH[n][f] = (v > 0.f) ? v : expm1f(v);
    }
    __syncthreads();

    // phase 3: h2 = elu(h1 @ W2 + b2)
    #pragma unroll
    for (int n = 0; n < NPB; n++) acc[n] = b2[f];
    #pragma unroll 4
    for (int k = 0; k < F_CH; k++) {
        float w = W2[k*F_CH + f];
        #pragma unroll
        for (int n = 0; n < NPB; n++) acc[n] = fmaf(sH[n][k], w, acc[n]);
    }
    for (int n = 0; n < NPB; n++) {
        float v = acc[n];
        v = (v > 0.f) ? v : expm1f(v);
        h2out[(nodeBase + n)*F_CH + f] = v;
    }
}

// ---------- kernel 5: grid-accelerated exact 3-NN, one thread per target ----------
__global__ __launch_bounds__(256) void knn_grid_kernel(const float* __restrict__ pos_skip,
    const int* __restrict__ cellstart, const float2* __restrict__ spos,
    const int* __restrict__ sidx, int* __restrict__ knn_idx, float* __restrict__ knn_w)
{
    int t = blockIdx.x * blockDim.x + threadIdx.x;
    if (t >= M_PTS) return;
    float tx = pos_skip[2*t], ty = pos_skip[2*t+1];
    const float h = 1.0f / G_GRID;
    int cx = min(max((int)(tx * G_GRID), 0), G_GRID - 1);
    int cy = min(max((int)(ty * G_GRID), 0), G_GRID - 1);

    // top-3 smallest keys; key = (bits(d2) << 32) | idx  -> exact top_k tie-break
    uint64_t k0 = UINT64_MAX, k1 = UINT64_MAX, k2 = UINT64_MAX;

    for (int r = 0; r < G_GRID; r++) {
        if (r > 0) {
            // all points in rings >= r are at distance >= (r-1)*h; stop if beaten
            float bound = ((r - 1) * h) * ((r - 1) * h) * 0.99999f;
            float d2cur = __uint_as_float((uint32_t)(k2 >> 32)); // NaN if unset -> no stop
            if (d2cur < bound) break;
        }
        int x0 = max(cx - r, 0), x1 = min(cx + r, G_GRID - 1);
        int y0 = max(cy - r, 0), y1 = min(cy + r, G_GRID - 1);
        for (int yy = y0; yy <= y1; yy++) {
            bool yedge = (yy == cy - r) || (yy == cy + r);
            for (int xx = x0; xx <= x1; xx++) {
                if (r > 0 && !yedge && xx != cx - r && xx != cx + r) continue;
                int c = yy * G_GRID + xx;
                int p0 = cellstart[c], p1 = cellstart[c + 1];
                for (int p = p0; p < p1; p++) {
                    float2 sp = spos[p];
                    float ddx = __fadd_rn(sp.x, -tx);  // matches (pos_skip - pos) sign-squared
                    float ddy = __fadd_rn(sp.y, -ty);
                    float dd = __fadd_rn(__fmul_rn(ddx, ddx), __fmul_rn(ddy, ddy));
                    uint64_t key = ((uint64_t)__float_as_uint(dd) << 32) | (uint32_t)sidx[p];
                    if (key < k2) {
                        if (key < k1) {
                            if (key < k0) { k2 = k1; k1 = k0; k0 = key; }
                            else          { k2 = k1; k1 = key; }
                        } else k2 = key;
                    }
                }
            }
        }
    }

    float d0 = __uint_as_float((uint32_t)(k0 >> 32));
    float d1 = __uint_as_float((uint32_t)(k1 >> 32));
    float d2 = __uint_as_float((uint32_t)(k2 >> 32));
    float w0 = 1.0f / fmaxf(d0, 1e-16f);
    float w1 = 1.0f / fmaxf(d1, 1e-16f);
    float w2 = 1.0f / fmaxf(d2, 1e-16f);
    float wsum = w0 + w1 + w2;
    knn_idx[t*3+0] = (int)(uint32_t)k0;
    knn_idx[t*3+1] = (int)(uint32_t)k1;
    knn_idx[t*3+2] = (int)(uint32_t)k2;
    knn_w[t*3+0] = w0 / wsum;
    knn_w[t*3+1] = w1 / wsum;
    knn_w[t*3+2] = w2 / wsum;
}

// ---------- kernel 6: weighted gather ----------
__global__ __launch_bounds__(128) void gather_kernel(const float* __restrict__ h2,
    const int* __restrict__ knn_idx, const float* __restrict__ knn_w,
    float* __restrict__ out)
{
    int m = blockIdx.x;
    int f = threadIdx.x;
    int j0 = knn_idx[m*3+0], j1 = knn_idx[m*3+1], j2 = knn_idx[m*3+2];
    float w0 = knn_w[m*3+0], w1 = knn_w[m*3+1], w2 = knn_w[m*3+2];
    float v = w0*h2[j0*F_CH+f] + w1*h2[j1*F_CH+f] + w2*h2[j2*F_CH+f];
    out[m*F_CH + f] = v;
}

extern "C" void kernel_launch(void* const* d_in, const int* in_sizes, int n_in,
                              void* d_out, int out_size, void* d_ws, size_t ws_size,
                              hipStream_t stream) {
    const float* x        = (const float*)d_in[0];
    const float* pos      = (const float*)d_in[1];
    const float* pos_skip = (const float*)d_in[2];
    const int*   ei       = (const int*)  d_in[3];
    const float* Wc       = (const float*)d_in[4];
    const float* bc       = (const float*)d_in[5];
    const float* W2       = (const float*)d_in[6];
    const float* b2       = (const float*)d_in[7];
    float* out = (float*)d_out;

    char* ws = (char*)d_ws;
    size_t off = 0;
    auto alloc = [&](size_t bytes) {
        void* p = ws + off;
        off = (off + bytes + 255) & ~(size_t)255;
        return p;
    };
    int*    cnt        = (int*)   alloc((size_t)N_NODES * 4);
    int*    cellcnt    = (int*)   alloc((size_t)N_CELLS * 4);
    int*    cursor     = (int*)   alloc((size_t)N_NODES * 4);
    int*    rowstart   = (int*)   alloc((size_t)(N_NODES + 1) * 4);
    int*    cellcursor = (int*)   alloc((size_t)N_CELLS * 4);
    int*    cellstart  = (int*)   alloc((size_t)(N_CELLS + 1) * 4);
    int*    esrc       = (int*)   alloc((size_t)E_EDGES * 4);
    float*  edx        = (float*) alloc((size_t)E_EDGES * 4);
    float*  edy        = (float*) alloc((size_t)E_EDGES * 4);
    float2* spos       = (float2*)alloc((size_t)N_NODES * 8);
    int*    sidx       = (int*)   alloc((size_t)N_NODES * 4);
    float*  h2         = (float*) alloc((size_t)N_NODES * F_CH * 4);
    int*    knn_idx    = (int*)   alloc((size_t)M_PTS * 3 * 4);
    float*  knn_w      = (float*) alloc((size_t)M_PTS * 3 * 4);

    hipMemsetAsync(cnt, 0, (size_t)N_NODES * 4, stream);
    hipMemsetAsync(cellcnt, 0, (size_t)N_CELLS * 4, stream);
    const int TOT = E_EDGES + N_NODES;
    count_all_kernel<<<(TOT + 255) / 256, 256, 0, stream>>>(ei, pos, cnt, cellcnt);
    scan_both_kernel<<<2, 1024, 0, stream>>>(cnt, rowstart, cursor, cellcnt, cellstart, cellcursor);
    scatter_all_kernel<<<(TOT + 255) / 256, 256, 0, stream>>>(ei, pos, cursor, esrc, edx, edy,
                                                              cellcursor, spos, sidx);
    conv_kernel<<<N_NODES / NPB, 128, 0, stream>>>(x, rowstart, esrc, edx, edy, Wc, bc, W2, b2, h2);
    knn_grid_kernel<<<(M_PTS + 255) / 256, 256, 0, stream>>>(pos_skip, cellstart, spos, sidx, knn_idx, knn_w);
    gather_kernel<<<M_PTS, 128, 0, stream>>>(h2, knn_idx, knn_w, out);
}

// Round 3
// 218.818 us; speedup vs baseline: 1.6006x; 1.0819x over previous
//
#include <hip/hip_runtime.h>
#include <hip/hip_bf16.h>
#include <math.h>
#include <float.h>
#include <stdint.h>

#define N_NODES 10000
#define M_PTS   20000
#define E_EDGES 160000
#define C_CH    128
#define F_CH    128
#define G_GRID  64
#define N_CELLS (G_GRID*G_GRID)
#define NPB     16      // nodes per block in fused conv kernel (one 16-row MFMA tile)

typedef __attribute__((ext_vector_type(8))) short short8;
typedef __attribute__((ext_vector_type(4))) float f32x4;

__device__ inline ushort f2bf(float v) {
    __hip_bfloat16 b = __float2bfloat16(v);
    return *reinterpret_cast<ushort*>(&b);
}
__device__ inline float bf2f(ushort u) {
    __hip_bfloat16 b = *reinterpret_cast<__hip_bfloat16*>(&u);
    return __bfloat162float(b);
}
__device__ inline float eluf(float v) { return (v > 0.f) ? v : expm1f(v); }

// ---------- kernel 1: count edges per dst AND points per grid cell ----------
__global__ void count_all_kernel(const int* __restrict__ ei, const float* __restrict__ pos,
                                 int* __restrict__ cnt, int* __restrict__ cellcnt) {
    int i = blockIdx.x * blockDim.x + threadIdx.x;
    if (i < E_EDGES) {
        atomicAdd(&cnt[ei[E_EDGES + i]], 1);
    } else if (i < E_EDGES + N_NODES) {
        int j = i - E_EDGES;
        float px = pos[2*j], py = pos[2*j+1];
        int cx = min(max((int)(px * G_GRID), 0), G_GRID - 1);
        int cy = min(max((int)(py * G_GRID), 0), G_GRID - 1);
        atomicAdd(&cellcnt[cy * G_GRID + cx], 1);
    }
}

// ---------- kernel 2: exclusive scans (block 0: edges-per-dst, block 1: cells) ----------
__global__ __launch_bounds__(1024) void scan_both_kernel(
    const int* __restrict__ cnt, int* __restrict__ rowstart, int* __restrict__ cursor,
    const int* __restrict__ cellcnt, int* __restrict__ cellstart, int* __restrict__ cellcursor) {
    __shared__ int part[1024];
    int t = threadIdx.x;
    const int n    = (blockIdx.x == 0) ? N_NODES : N_CELLS;
    const int CH   = (blockIdx.x == 0) ? 10 : 4;
    const int* in  = (blockIdx.x == 0) ? cnt : cellcnt;
    int* outs      = (blockIdx.x == 0) ? rowstart : cellstart;
    int* outc      = (blockIdx.x == 0) ? cursor : cellcursor;

    int base = t * CH;
    int local[10];
    int s = 0;
    for (int k = 0; k < CH; k++) {
        int idx = base + k;
        int v = (idx < n) ? in[idx] : 0;
        local[k] = s;
        s += v;
    }
    part[t] = s;
    __syncthreads();
    for (int off = 1; off < 1024; off <<= 1) {
        int v = (t >= off) ? part[t - off] : 0;
        __syncthreads();
        part[t] += v;
        __syncthreads();
    }
    int offset = (t > 0) ? part[t - 1] : 0;
    for (int k = 0; k < CH; k++) {
        int idx = base + k;
        if (idx < n) {
            int rs = offset + local[k];
            outs[idx] = rs;
            outc[idx] = rs;
        }
    }
    if (t == 1023) outs[n] = part[1023];
}

// ---------- kernel 3: scatter edges into CSR; scatter points into cells ----------
__global__ void scatter_all_kernel(const int* __restrict__ ei, const float* __restrict__ pos,
                                   int* __restrict__ cursor, int* __restrict__ esrc,
                                   float* __restrict__ edx, float* __restrict__ edy,
                                   int* __restrict__ cellcursor, float2* __restrict__ spos,
                                   int* __restrict__ sidx) {
    int i = blockIdx.x * blockDim.x + threadIdx.x;
    if (i < E_EDGES) {
        int src = ei[i];
        int dst = ei[E_EDGES + i];
        float dxv = pos[2*dst]     - pos[2*src];
        float dyv = pos[2*dst + 1] - pos[2*src + 1];
        float r2 = dxv*dxv + dyv*dyv;
        float scale = 1.0f / (r2 + 0.01f);
        int p = atomicAdd(&cursor[dst], 1);
        esrc[p] = src;
        edx[p] = dxv * scale;
        edy[p] = dyv * scale;
    } else if (i < E_EDGES + N_NODES) {
        int j = i - E_EDGES;
        float px = pos[2*j], py = pos[2*j+1];
        int cx = min(max((int)(px * G_GRID), 0), G_GRID - 1);
        int cy = min(max((int)(py * G_GRID), 0), G_GRID - 1);
        int p = atomicAdd(&cellcursor[cy * G_GRID + cx], 1);
        spos[p] = make_float2(px, py);
        sidx[p] = j;
    }
}

// ---------- kernel 4: transpose W into [n][k] bf16 hi/lo planes ----------
__global__ void prep_w_kernel(const float* __restrict__ Wc, const float* __restrict__ W2,
                              ushort* __restrict__ Wct_h, ushort* __restrict__ Wct_l,
                              ushort* __restrict__ W2t_h, ushort* __restrict__ W2t_l) {
    int i = blockIdx.x * blockDim.x + threadIdx.x;
    if (i < 4*C_CH*F_CH) {
        int k = i >> 7, n = i & 127;      // Wc[k][n]
        float v = Wc[i];
        ushort h = f2bf(v);
        ushort l = f2bf(v - bf2f(h));
        Wct_h[n*512 + k] = h;
        Wct_l[n*512 + k] = l;
    } else if (i < 4*C_CH*F_CH + F_CH*F_CH) {
        int j = i - 4*C_CH*F_CH;
        int k = j >> 7, n = j & 127;      // W2[k][n]
        float v = W2[j];
        ushort h = f2bf(v);
        ushort l = f2bf(v - bf2f(h));
        W2t_h[n*128 + k] = h;
        W2t_l[n*128 + k] = l;
    }
}

// ---------- kernel 5: fused aggregation + MFMA GEMM1 + ELU + MFMA GEMM2 + ELU ----------
// block = 128 threads (2 waves), 16 nodes per block. A = [16 rows x 512 k] hi/lo bf16 in LDS.
// wave w computes output cols w*64 .. w*64+63 for all 16 rows.
#define A_STRIDE 520   // ushorts per row: 512 + 8 pad (1040 B, 16B-aligned, 2-way bank = free)
#define H_STRIDE 136   // ushorts per row: 128 + 8 pad (272 B)
__global__ __launch_bounds__(128) void fused_conv_kernel(const float* __restrict__ x,
    const int* __restrict__ rowstart, const int* __restrict__ esrc,
    const float* __restrict__ edx, const float* __restrict__ edy,
    const ushort* __restrict__ Wct_h, const ushort* __restrict__ Wct_l,
    const ushort* __restrict__ W2t_h, const ushort* __restrict__ W2t_l,
    const float* __restrict__ bc, const float* __restrict__ b2,
    float* __restrict__ h2out)
{
    __shared__ ushort sA_h[NPB * A_STRIDE];
    __shared__ ushort sA_l[NPB * A_STRIDE];
    __shared__ ushort sH_h[NPB * H_STRIDE];
    __shared__ ushort sH_l[NPB * H_STRIDE];

    const int f = threadIdx.x;            // 0..127 : channel
    const int nodeBase = blockIdx.x * NPB;
    const int lane = threadIdx.x & 63;
    const int wave = threadIdx.x >> 6;
    const int col16 = lane & 15;
    const int quad  = lane >> 4;

    // ---- phase 1: aggregation, thread f owns channel f for all 16 nodes ----
    for (int n = 0; n < NPB; n++) {
        int i = nodeBase + n;
        float xi = x[i*C_CH + f];
        int p0 = rowstart[i], p1 = rowstart[i+1];
        float a1 = 0.f, a2 = 0.f, a3 = 0.f;
        int p = p0;
        for (; p + 3 < p1; p += 4) {
            int s0 = esrc[p], s1 = esrc[p+1], s2 = esrc[p+2], s3 = esrc[p+3];
            float x0 = x[s0*C_CH + f], x1 = x[s1*C_CH + f];
            float x2 = x[s2*C_CH + f], x3 = x[s3*C_CH + f];
            float dx0 = edx[p], dx1 = edx[p+1], dx2 = edx[p+2], dx3 = edx[p+3];
            float dy0 = edy[p], dy1 = edy[p+1], dy2 = edy[p+2], dy3 = edy[p+3];
            a1 = fmaf(xi - x0, dx0, a1); a2 = fmaf(xi - x0, dy0, a2); a3 += x0;
            a1 = fmaf(xi - x1, dx1, a1); a2 = fmaf(xi - x1, dy1, a2); a3 += x1;
            a1 = fmaf(xi - x2, dx2, a1); a2 = fmaf(xi - x2, dy2, a2); a3 += x2;
            a1 = fmaf(xi - x3, dx3, a1); a2 = fmaf(xi - x3, dy3, a2); a3 += x3;
        }
        for (; p < p1; p++) {
            int s = esrc[p];
            float xj = x[s*C_CH + f];
            float d = xi - xj;
            a1 = fmaf(d, edx[p], a1);
            a2 = fmaf(d, edy[p], a2);
            a3 += xj;
        }
        float inv = 1.0f / fmaxf((float)(p1 - p0), 1.0f);
        float v0 = a1 * inv, v1 = a2 * inv, v2 = a3 * inv, v3 = xi;
        ushort h0 = f2bf(v0), h1v = f2bf(v1), h2v = f2bf(v2), h3 = f2bf(v3);
        int b = n * A_STRIDE;
        sA_h[b + f]       = h0;  sA_l[b + f]       = f2bf(v0 - bf2f(h0));
        sA_h[b + 128 + f] = h1v; sA_l[b + 128 + f] = f2bf(v1 - bf2f(h1v));
        sA_h[b + 256 + f] = h2v; sA_l[b + 256 + f] = f2bf(v2 - bf2f(h2v));
        sA_h[b + 384 + f] = h3;  sA_l[b + 384 + f] = f2bf(v3 - bf2f(h3));
    }
    __syncthreads();

    // ---- phase 2: GEMM1 (16x128 rows x cols, K=512), wave covers 4 n-tiles ----
    const int row = col16;                 // A row = lane&15
    f32x4 acc[4] = {f32x4{0,0,0,0}, f32x4{0,0,0,0}, f32x4{0,0,0,0}, f32x4{0,0,0,0}};
    int ncol[4]; float bcv[4], b2v[4];
    #pragma unroll
    for (int nt = 0; nt < 4; nt++) {
        ncol[nt] = wave*64 + nt*16 + col16;
        bcv[nt] = bc[ncol[nt]];
        b2v[nt] = b2[ncol[nt]];
    }
    for (int ks = 0; ks < 16; ks++) {
        int kb = ks*32 + quad*8;
        short8 ah = *(const short8*)&sA_h[row*A_STRIDE + kb];
        short8 al = *(const short8*)&sA_l[row*A_STRIDE + kb];
        #pragma unroll
        for (int nt = 0; nt < 4; nt++) {
            short8 bh = *(const short8*)(Wct_h + (size_t)ncol[nt]*512 + kb);
            short8 bl = *(const short8*)(Wct_l + (size_t)ncol[nt]*512 + kb);
            acc[nt] = __builtin_amdgcn_mfma_f32_16x16x32_bf16(ah, bh, acc[nt], 0, 0, 0);
            acc[nt] = __builtin_amdgcn_mfma_f32_16x16x32_bf16(ah, bl, acc[nt], 0, 0, 0);
            acc[nt] = __builtin_amdgcn_mfma_f32_16x16x32_bf16(al, bh, acc[nt], 0, 0, 0);
        }
    }

    // ---- epilogue 1: +bc, ELU, stage h1 hi/lo to LDS (C/D layout: col=lane&15, row=quad*4+reg)
    #pragma unroll
    for (int nt = 0; nt < 4; nt++) {
        #pragma unroll
        for (int r = 0; r < 4; r++) {
            int rr = quad*4 + r;
            float v = eluf(acc[nt][r] + bcv[nt]);
            ushort hh = f2bf(v);
            sH_h[rr*H_STRIDE + ncol[nt]] = hh;
            sH_l[rr*H_STRIDE + ncol[nt]] = f2bf(v - bf2f(hh));
        }
    }
    __syncthreads();

    // ---- phase 3: GEMM2 (16x128, K=128) ----
    f32x4 acc2[4] = {f32x4{0,0,0,0}, f32x4{0,0,0,0}, f32x4{0,0,0,0}, f32x4{0,0,0,0}};
    for (int ks = 0; ks < 4; ks++) {
        int kb = ks*32 + quad*8;
        short8 ah = *(const short8*)&sH_h[row*H_STRIDE + kb];
        short8 al = *(const short8*)&sH_l[row*H_STRIDE + kb];
        #pragma unroll
        for (int nt = 0; nt < 4; nt++) {
            short8 bh = *(const short8*)(W2t_h + ncol[nt]*128 + kb);
            short8 bl = *(const short8*)(W2t_l + ncol[nt]*128 + kb);
            acc2[nt] = __builtin_amdgcn_mfma_f32_16x16x32_bf16(ah, bh, acc2[nt], 0, 0, 0);
            acc2[nt] = __builtin_amdgcn_mfma_f32_16x16x32_bf16(ah, bl, acc2[nt], 0, 0, 0);
            acc2[nt] = __builtin_amdgcn_mfma_f32_16x16x32_bf16(al, bh, acc2[nt], 0, 0, 0);
        }
    }

    // ---- epilogue 2: +b2, ELU, store h2 fp32 ----
    #pragma unroll
    for (int nt = 0; nt < 4; nt++) {
        #pragma unroll
        for (int r = 0; r < 4; r++) {
            int node = nodeBase + quad*4 + r;
            float v = eluf(acc2[nt][r] + b2v[nt]);
            h2out[(size_t)node*F_CH + ncol[nt]] = v;
        }
    }
}

// ---------- kernel 6: grid-accelerated exact 3-NN, one thread per target ----------
__global__ __launch_bounds__(256) void knn_grid_kernel(const float* __restrict__ pos_skip,
    const int* __restrict__ cellstart, const float2* __restrict__ spos,
    const int* __restrict__ sidx, int* __restrict__ knn_idx, float* __restrict__ knn_w)
{
    int t = blockIdx.x * blockDim.x + threadIdx.x;
    if (t >= M_PTS) return;
    float tx = pos_skip[2*t], ty = pos_skip[2*t+1];
    const float h = 1.0f / G_GRID;
    int cx = min(max((int)(tx * G_GRID), 0), G_GRID - 1);
    int cy = min(max((int)(ty * G_GRID), 0), G_GRID - 1);

    uint64_t k0 = UINT64_MAX, k1 = UINT64_MAX, k2 = UINT64_MAX;

    for (int r = 0; r < G_GRID; r++) {
        if (r > 0) {
            float bound = ((r - 1) * h) * ((r - 1) * h) * 0.99999f;
            float d2cur = __uint_as_float((uint32_t)(k2 >> 32));
            if (d2cur < bound) break;
        }
        int x0 = max(cx - r, 0), x1 = min(cx + r, G_GRID - 1);
        int y0 = max(cy - r, 0), y1 = min(cy + r, G_GRID - 1);
        for (int yy = y0; yy <= y1; yy++) {
            bool yedge = (yy == cy - r) || (yy == cy + r);
            for (int xx = x0; xx <= x1; xx++) {
                if (r > 0 && !yedge && xx != cx - r && xx != cx + r) continue;
                int c = yy * G_GRID + xx;
                int p0 = cellstart[c], p1 = cellstart[c + 1];
                for (int p = p0; p < p1; p++) {
                    float2 sp = spos[p];
                    float ddx = __fadd_rn(sp.x, -tx);
                    float ddy = __fadd_rn(sp.y, -ty);
                    float dd = __fadd_rn(__fmul_rn(ddx, ddx), __fmul_rn(ddy, ddy));
                    uint64_t key = ((uint64_t)__float_as_uint(dd) << 32) | (uint32_t)sidx[p];
                    if (key < k2) {
                        if (key < k1) {
                            if (key < k0) { k2 = k1; k1 = k0; k0 = key; }
                            else          { k2 = k1; k1 = key; }
                        } else k2 = key;
                    }
                }
            }
        }
    }

    float d0 = __uint_as_float((uint32_t)(k0 >> 32));
    float d1 = __uint_as_float((uint32_t)(k1 >> 32));
    float d2 = __uint_as_float((uint32_t)(k2 >> 32));
    float w0 = 1.0f / fmaxf(d0, 1e-16f);
    float w1 = 1.0f / fmaxf(d1, 1e-16f);
    float w2 = 1.0f / fmaxf(d2, 1e-16f);
    float wsum = w0 + w1 + w2;
    knn_idx[t*3+0] = (int)(uint32_t)k0;
    knn_idx[t*3+1] = (int)(uint32_t)k1;
    knn_idx[t*3+2] = (int)(uint32_t)k2;
    knn_w[t*3+0] = w0 / wsum;
    knn_w[t*3+1] = w1 / wsum;
    knn_w[t*3+2] = w2 / wsum;
}

// ---------- kernel 7: weighted gather, one wave per target ----------
__global__ __launch_bounds__(256) void gather_kernel(const float* __restrict__ h2,
    const int* __restrict__ knn_idx, const float* __restrict__ knn_w,
    float* __restrict__ out)
{
    int m = blockIdx.x * 4 + (threadIdx.x >> 6);
    int lane = threadIdx.x & 63;
    const float2* h2v = (const float2*)h2;
    int j0 = knn_idx[m*3+0], j1 = knn_idx[m*3+1], j2 = knn_idx[m*3+2];
    float w0 = knn_w[m*3+0], w1 = knn_w[m*3+1], w2 = knn_w[m*3+2];
    float2 a = h2v[j0*64 + lane], b = h2v[j1*64 + lane], c = h2v[j2*64 + lane];
    float2 v;
    v.x = w0*a.x + w1*b.x + w2*c.x;
    v.y = w0*a.y + w1*b.y + w2*c.y;
    ((float2*)out)[m*64 + lane] = v;
}

extern "C" void kernel_launch(void* const* d_in, const int* in_sizes, int n_in,
                              void* d_out, int out_size, void* d_ws, size_t ws_size,
                              hipStream_t stream) {
    const float* x        = (const float*)d_in[0];
    const float* pos      = (const float*)d_in[1];
    const float* pos_skip = (const float*)d_in[2];
    const int*   ei       = (const int*)  d_in[3];
    const float* Wc       = (const float*)d_in[4];
    const float* bc       = (const float*)d_in[5];
    const float* W2       = (const float*)d_in[6];
    const float* b2       = (const float*)d_in[7];
    float* out = (float*)d_out;

    char* ws = (char*)d_ws;
    size_t off = 0;
    auto alloc = [&](size_t bytes) {
        void* p = ws + off;
        off = (off + bytes + 255) & ~(size_t)255;
        return p;
    };
    int*    cnt        = (int*)   alloc((size_t)N_NODES * 4);
    int*    cellcnt    = (int*)   alloc((size_t)N_CELLS * 4);
    int*    cursor     = (int*)   alloc((size_t)N_NODES * 4);
    int*    rowstart   = (int*)   alloc((size_t)(N_NODES + 1) * 4);
    int*    cellcursor = (int*)   alloc((size_t)N_CELLS * 4);
    int*    cellstart  = (int*)   alloc((size_t)(N_CELLS + 1) * 4);
    int*    esrc       = (int*)   alloc((size_t)E_EDGES * 4);
    float*  edx        = (float*) alloc((size_t)E_EDGES * 4);
    float*  edy        = (float*) alloc((size_t)E_EDGES * 4);
    float2* spos       = (float2*)alloc((size_t)N_NODES * 8);
    int*    sidx       = (int*)   alloc((size_t)N_NODES * 4);
    float*  h2         = (float*) alloc((size_t)N_NODES * F_CH * 4);
    int*    knn_idx    = (int*)   alloc((size_t)M_PTS * 3 * 4);
    float*  knn_w      = (float*) alloc((size_t)M_PTS * 3 * 4);
    ushort* Wct_h      = (ushort*)alloc((size_t)F_CH * 512 * 2);
    ushort* Wct_l      = (ushort*)alloc((size_t)F_CH * 512 * 2);
    ushort* W2t_h      = (ushort*)alloc((size_t)F_CH * 128 * 2);
    ushort* W2t_l      = (ushort*)alloc((size_t)F_CH * 128 * 2);

    hipMemsetAsync(cnt, 0, (size_t)N_NODES * 4, stream);
    hipMemsetAsync(cellcnt, 0, (size_t)N_CELLS * 4, stream);
    const int TOT = E_EDGES + N_NODES;
    count_all_kernel<<<(TOT + 255) / 256, 256, 0, stream>>>(ei, pos, cnt, cellcnt);
    scan_both_kernel<<<2, 1024, 0, stream>>>(cnt, rowstart, cursor, cellcnt, cellstart, cellcursor);
    scatter_all_kernel<<<(TOT + 255) / 256, 256, 0, stream>>>(ei, pos, cursor, esrc, edx, edy,
                                                              cellcursor, spos, sidx);
    prep_w_kernel<<<(4*C_CH*F_CH + F_CH*F_CH + 255) / 256, 256, 0, stream>>>(
        Wc, W2, Wct_h, Wct_l, W2t_h, W2t_l);
    fused_conv_kernel<<<N_NODES / NPB, 128, 0, stream>>>(x, rowstart, esrc, edx, edy,
        Wct_h, Wct_l, W2t_h, W2t_l, bc, b2, h2);
    knn_grid_kernel<<<(M_PTS + 255) / 256, 256, 0, stream>>>(pos_skip, cellstart, spos, sidx, knn_idx, knn_w);
    gather_kernel<<<M_PTS / 4, 256, 0, stream>>>(h2, knn_idx, knn_w, out);
}

// Round 5
// 198.914 us; speedup vs baseline: 1.7608x; 1.1001x over previous
//
#include <hip/hip_runtime.h>
#include <hip/hip_bf16.h>
#include <math.h>
#include <float.h>
#include <stdint.h>

#define N_NODES 10000
#define M_PTS   20000
#define E_EDGES 160000
#define C_CH    128
#define F_CH    128
#define G_GRID  64
#define N_CELLS (G_GRID*G_GRID)
#define NPB     16      // nodes per block in gemm kernel (one 16-row MFMA tile)

typedef __attribute__((ext_vector_type(8))) short short8;
typedef __attribute__((ext_vector_type(4))) float f32x4;

__device__ inline ushort f2bf(float v) {
    __hip_bfloat16 b = __float2bfloat16(v);
    return *reinterpret_cast<ushort*>(&b);
}
__device__ inline float bf2f(ushort u) {
    __hip_bfloat16 b = *reinterpret_cast<__hip_bfloat16*>(&u);
    return __bfloat162float(b);
}
__device__ inline float eluf(float v) { return (v > 0.f) ? v : expm1f(v); }

// ---------- kernel 1: count edges per dst AND points per grid cell ----------
__global__ void count_all_kernel(const int* __restrict__ ei, const float* __restrict__ pos,
                                 int* __restrict__ cnt, int* __restrict__ cellcnt) {
    int i = blockIdx.x * blockDim.x + threadIdx.x;
    if (i < E_EDGES) {
        atomicAdd(&cnt[ei[E_EDGES + i]], 1);
    } else if (i < E_EDGES + N_NODES) {
        int j = i - E_EDGES;
        float px = pos[2*j], py = pos[2*j+1];
        int cx = min(max((int)(px * G_GRID), 0), G_GRID - 1);
        int cy = min(max((int)(py * G_GRID), 0), G_GRID - 1);
        atomicAdd(&cellcnt[cy * G_GRID + cx], 1);
    }
}

// ---------- kernel 2: exclusive scans (block 0: edges-per-dst, block 1: cells) ----------
__global__ __launch_bounds__(1024) void scan_both_kernel(
    const int* __restrict__ cnt, int* __restrict__ rowstart, int* __restrict__ cursor,
    const int* __restrict__ cellcnt, int* __restrict__ cellstart, int* __restrict__ cellcursor) {
    __shared__ int part[1024];
    int t = threadIdx.x;
    const int n    = (blockIdx.x == 0) ? N_NODES : N_CELLS;
    const int CH   = (blockIdx.x == 0) ? 10 : 4;
    const int* in  = (blockIdx.x == 0) ? cnt : cellcnt;
    int* outs      = (blockIdx.x == 0) ? rowstart : cellstart;
    int* outc      = (blockIdx.x == 0) ? cursor : cellcursor;

    int base = t * CH;
    int local[10];
    int s = 0;
    for (int k = 0; k < CH; k++) {
        int idx = base + k;
        int v = (idx < n) ? in[idx] : 0;
        local[k] = s;
        s += v;
    }
    part[t] = s;
    __syncthreads();
    for (int off = 1; off < 1024; off <<= 1) {
        int v = (t >= off) ? part[t - off] : 0;
        __syncthreads();
        part[t] += v;
        __syncthreads();
    }
    int offset = (t > 0) ? part[t - 1] : 0;
    for (int k = 0; k < CH; k++) {
        int idx = base + k;
        if (idx < n) {
            int rs = offset + local[k];
            outs[idx] = rs;
            outc[idx] = rs;
        }
    }
    if (t == 1023) outs[n] = part[1023];
}

// ---------- kernel 3: scatter edges into CSR; scatter points into cells ----------
__global__ void scatter_all_kernel(const int* __restrict__ ei, const float* __restrict__ pos,
                                   int* __restrict__ cursor, int* __restrict__ esrc,
                                   float* __restrict__ edx, float* __restrict__ edy,
                                   int* __restrict__ cellcursor, float2* __restrict__ spos,
                                   int* __restrict__ sidx) {
    int i = blockIdx.x * blockDim.x + threadIdx.x;
    if (i < E_EDGES) {
        int src = ei[i];
        int dst = ei[E_EDGES + i];
        float dxv = pos[2*dst]     - pos[2*src];
        float dyv = pos[2*dst + 1] - pos[2*src + 1];
        float r2 = dxv*dxv + dyv*dyv;
        float scale = 1.0f / (r2 + 0.01f);
        int p = atomicAdd(&cursor[dst], 1);
        esrc[p] = src;
        edx[p] = dxv * scale;
        edy[p] = dyv * scale;
    } else if (i < E_EDGES + N_NODES) {
        int j = i - E_EDGES;
        float px = pos[2*j], py = pos[2*j+1];
        int cx = min(max((int)(px * G_GRID), 0), G_GRID - 1);
        int cy = min(max((int)(py * G_GRID), 0), G_GRID - 1);
        int p = atomicAdd(&cellcursor[cy * G_GRID + cx], 1);
        spos[p] = make_float2(px, py);
        sidx[p] = j;
    }
}

// ---------- kernel 4: transpose W into [n][k] bf16 hi/lo planes ----------
__global__ void prep_w_kernel(const float* __restrict__ Wc, const float* __restrict__ W2,
                              ushort* __restrict__ Wct_h, ushort* __restrict__ Wct_l,
                              ushort* __restrict__ W2t_h, ushort* __restrict__ W2t_l) {
    int i = blockIdx.x * blockDim.x + threadIdx.x;
    if (i < 4*C_CH*F_CH) {
        int k = i >> 7, n = i & 127;      // Wc[k][n]
        float v = Wc[i];
        ushort h = f2bf(v);
        ushort l = f2bf(v - bf2f(h));
        Wct_h[n*512 + k] = h;
        Wct_l[n*512 + k] = l;
    } else if (i < 4*C_CH*F_CH + F_CH*F_CH) {
        int j = i - 4*C_CH*F_CH;
        int k = j >> 7, n = j & 127;      // W2[k][n]
        float v = W2[j];
        ushort h = f2bf(v);
        ushort l = f2bf(v - bf2f(h));
        W2t_h[n*128 + k] = h;
        W2t_l[n*128 + k] = l;
    }
}

// ---------- kernel 5: aggregation, one wave per node ----------
// Writes A row [agg_dx(128) | agg_dy(128) | agg_mean(128) | x(128)] as bf16 hi/lo planes.
__global__ __launch_bounds__(256) void agg_kernel(const float* __restrict__ x,
    const int* __restrict__ rowstart, const int* __restrict__ esrc,
    const float* __restrict__ edx, const float* __restrict__ edy,
    ushort* __restrict__ aggA_h, ushort* __restrict__ aggA_l)
{
    int node = blockIdx.x * 4 + (threadIdx.x >> 6);
    int lane = threadIdx.x & 63;
    const float2* xv = (const float2*)x;
    float2 xi = xv[(size_t)node*64 + lane];
    int p0 = rowstart[node], p1 = rowstart[node+1];
    float a1x = 0.f, a1y = 0.f, a2x = 0.f, a2y = 0.f, a3x = 0.f, a3y = 0.f;
    int p = p0;
    for (; p + 3 < p1; p += 4) {
        int s0 = esrc[p], s1 = esrc[p+1], s2 = esrc[p+2], s3 = esrc[p+3];
        float2 x0 = xv[(size_t)s0*64 + lane];
        float2 x1 = xv[(size_t)s1*64 + lane];
        float2 x2 = xv[(size_t)s2*64 + lane];
        float2 x3 = xv[(size_t)s3*64 + lane];
        float dx0 = edx[p], dx1 = edx[p+1], dx2 = edx[p+2], dx3 = edx[p+3];
        float dy0 = edy[p], dy1 = edy[p+1], dy2 = edy[p+2], dy3 = edy[p+3];
        a1x = fmaf(xi.x - x0.x, dx0, a1x); a1y = fmaf(xi.y - x0.y, dx0, a1y);
        a2x = fmaf(xi.x - x0.x, dy0, a2x); a2y = fmaf(xi.y - x0.y, dy0, a2y);
        a3x += x0.x; a3y += x0.y;
        a1x = fmaf(xi.x - x1.x, dx1, a1x); a1y = fmaf(xi.y - x1.y, dx1, a1y);
        a2x = fmaf(xi.x - x1.x, dy1, a2x); a2y = fmaf(xi.y - x1.y, dy1, a2y);
        a3x += x1.x; a3y += x1.y;
        a1x = fmaf(xi.x - x2.x, dx2, a1x); a1y = fmaf(xi.y - x2.y, dx2, a1y);
        a2x = fmaf(xi.x - x2.x, dy2, a2x); a2y = fmaf(xi.y - x2.y, dy2, a2y);
        a3x += x2.x; a3y += x2.y;
        a1x = fmaf(xi.x - x3.x, dx3, a1x); a1y = fmaf(xi.y - x3.y, dx3, a1y);
        a2x = fmaf(xi.x - x3.x, dy3, a2x); a2y = fmaf(xi.y - x3.y, dy3, a2y);
        a3x += x3.x; a3y += x3.y;
    }
    for (; p < p1; p++) {
        int s = esrc[p];
        float2 xj = xv[(size_t)s*64 + lane];
        float dxe = edx[p], dye = edy[p];
        a1x = fmaf(xi.x - xj.x, dxe, a1x); a1y = fmaf(xi.y - xj.y, dxe, a1y);
        a2x = fmaf(xi.x - xj.x, dye, a2x); a2y = fmaf(xi.y - xj.y, dye, a2y);
        a3x += xj.x; a3y += xj.y;
    }
    float inv = 1.0f / fmaxf((float)(p1 - p0), 1.0f);
    float vals[4][2] = {{a1x*inv, a1y*inv}, {a2x*inv, a2y*inv}, {a3x*inv, a3y*inv}, {xi.x, xi.y}};
    size_t rb = (size_t)node * 512;
    int c0 = 2*lane;
    #pragma unroll
    for (int seg = 0; seg < 4; seg++) {
        ushort hx = f2bf(vals[seg][0]), hy = f2bf(vals[seg][1]);
        ushort lx = f2bf(vals[seg][0] - bf2f(hx)), ly = f2bf(vals[seg][1] - bf2f(hy));
        *(uint*)&aggA_h[rb + seg*128 + c0] = (uint)hx | ((uint)hy << 16);
        *(uint*)&aggA_l[rb + seg*128 + c0] = (uint)lx | ((uint)ly << 16);
    }
}

// ---------- kernel 6: MFMA GEMM1 + ELU + MFMA GEMM2 + ELU ----------
#define A_STRIDE 520   // ushorts per row: 512 + 8 pad
#define H_STRIDE 136   // ushorts per row: 128 + 8 pad
__global__ __launch_bounds__(128) void gemm_kernel(
    const ushort* __restrict__ aggA_h, const ushort* __restrict__ aggA_l,
    const ushort* __restrict__ Wct_h, const ushort* __restrict__ Wct_l,
    const ushort* __restrict__ W2t_h, const ushort* __restrict__ W2t_l,
    const float* __restrict__ bc, const float* __restrict__ b2,
    float* __restrict__ h2out)
{
    __shared__ alignas(16) ushort sA_h[NPB * A_STRIDE];
    __shared__ alignas(16) ushort sA_l[NPB * A_STRIDE];
    __shared__ alignas(16) ushort sH_h[NPB * H_STRIDE];
    __shared__ alignas(16) ushort sH_l[NPB * H_STRIDE];

    const int tid = threadIdx.x;
    const int nodeBase = blockIdx.x * NPB;
    const int lane = tid & 63;
    const int wave = tid >> 6;
    const int col16 = lane & 15;
    const int quad  = lane >> 4;

    // stage A tile (16 rows x 512 ushorts per plane) into padded LDS
    {
        const uint2* gh = (const uint2*)(aggA_h + (size_t)nodeBase * 512);
        const uint2* gl = (const uint2*)(aggA_l + (size_t)nodeBase * 512);
        uint2* sh = (uint2*)sA_h;
        uint2* sl = (uint2*)sA_l;
        #pragma unroll
        for (int r = 0; r < NPB; r++) {
            sh[r*130 + tid] = gh[r*128 + tid];
            sl[r*130 + tid] = gl[r*128 + tid];
        }
    }
    __syncthreads();

    const int row = col16;
    f32x4 acc[4] = {f32x4{0,0,0,0}, f32x4{0,0,0,0}, f32x4{0,0,0,0}, f32x4{0,0,0,0}};
    int ncol[4]; float bcv[4], b2v[4];
    #pragma unroll
    for (int nt = 0; nt < 4; nt++) {
        ncol[nt] = wave*64 + nt*16 + col16;
        bcv[nt] = bc[ncol[nt]];
        b2v[nt] = b2[ncol[nt]];
    }
    for (int ks = 0; ks < 16; ks++) {
        int kb = ks*32 + quad*8;
        short8 ah = *(const short8*)&sA_h[row*A_STRIDE + kb];
        short8 al = *(const short8*)&sA_l[row*A_STRIDE + kb];
        #pragma unroll
        for (int nt = 0; nt < 4; nt++) {
            short8 bh = *(const short8*)(Wct_h + (size_t)ncol[nt]*512 + kb);
            short8 bl = *(const short8*)(Wct_l + (size_t)ncol[nt]*512 + kb);
            acc[nt] = __builtin_amdgcn_mfma_f32_16x16x32_bf16(ah, bh, acc[nt], 0, 0, 0);
            acc[nt] = __builtin_amdgcn_mfma_f32_16x16x32_bf16(ah, bl, acc[nt], 0, 0, 0);
            acc[nt] = __builtin_amdgcn_mfma_f32_16x16x32_bf16(al, bh, acc[nt], 0, 0, 0);
        }
    }

    #pragma unroll
    for (int nt = 0; nt < 4; nt++) {
        #pragma unroll
        for (int r = 0; r < 4; r++) {
            int rr = quad*4 + r;
            float v = eluf(acc[nt][r] + bcv[nt]);
            ushort hh = f2bf(v);
            sH_h[rr*H_STRIDE + ncol[nt]] = hh;
            sH_l[rr*H_STRIDE + ncol[nt]] = f2bf(v - bf2f(hh));
        }
    }
    __syncthreads();

    f32x4 acc2[4] = {f32x4{0,0,0,0}, f32x4{0,0,0,0}, f32x4{0,0,0,0}, f32x4{0,0,0,0}};
    for (int ks = 0; ks < 4; ks++) {
        int kb = ks*32 + quad*8;
        short8 ah = *(const short8*)&sH_h[row*H_STRIDE + kb];
        short8 al = *(const short8*)&sH_l[row*H_STRIDE + kb];
        #pragma unroll
        for (int nt = 0; nt < 4; nt++) {
            short8 bh = *(const short8*)(W2t_h + ncol[nt]*128 + kb);
            short8 bl = *(const short8*)(W2t_l + ncol[nt]*128 + kb);
            acc2[nt] = __builtin_amdgcn_mfma_f32_16x16x32_bf16(ah, bh, acc2[nt], 0, 0, 0);
            acc2[nt] = __builtin_amdgcn_mfma_f32_16x16x32_bf16(ah, bl, acc2[nt], 0, 0, 0);
            acc2[nt] = __builtin_amdgcn_mfma_f32_16x16x32_bf16(al, bh, acc2[nt], 0, 0, 0);
        }
    }

    #pragma unroll
    for (int nt = 0; nt < 4; nt++) {
        #pragma unroll
        for (int r = 0; r < 4; r++) {
            int node = nodeBase + quad*4 + r;
            float v = eluf(acc2[nt][r] + b2v[nt]);
            h2out[(size_t)node*F_CH + ncol[nt]] = v;
        }
    }
}

// ---------- kernel 7: grid 3-NN, 4 sub-lanes per target ----------
// Each candidate cell is scanned by exactly ONE sub-lane, so the 4 local
// top-3 sets stay disjoint. Merges for the stop test go into TEMPORARIES
// only (each butterfly step merges disjoint sets -> no duplicate keys);
// locals keep accumulating own candidates. Final answer = last merged temps.
__device__ inline void insert3(uint64_t key, uint64_t& k0, uint64_t& k1, uint64_t& k2) {
    bool lt2 = key < k2, lt1 = key < k1, lt0 = key < k0;
    k2 = lt1 ? k1 : (lt2 ? key : k2);
    k1 = lt0 ? k0 : (lt1 ? key : k1);
    k0 = lt0 ? key : k0;
}
__global__ __launch_bounds__(256) void knn_grid_kernel(const float* __restrict__ pos_skip,
    const int* __restrict__ cellstart, const float2* __restrict__ spos,
    const int* __restrict__ sidx, int* __restrict__ knn_idx, float* __restrict__ knn_w)
{
    int gt = blockIdx.x * blockDim.x + threadIdx.x;
    int t = gt >> 2;
    int sub = gt & 3;
    if (t >= M_PTS) return;
    float tx = pos_skip[2*t], ty = pos_skip[2*t+1];
    const float h = 1.0f / G_GRID;
    int cx = min(max((int)(tx * G_GRID), 0), G_GRID - 1);
    int cy = min(max((int)(ty * G_GRID), 0), G_GRID - 1);

    uint64_t k0 = UINT64_MAX, k1 = UINT64_MAX, k2 = UINT64_MAX;   // own candidates only
    uint64_t m0 = UINT64_MAX, m1 = UINT64_MAX, m2 = UINT64_MAX;   // merged (final answer)

    for (int r = 0; ; r++) {
        if (r > 0) {
            // merge own top-3 across the 4 sub-lanes into temporaries
            m0 = k0; m1 = k1; m2 = k2;
            #pragma unroll
            for (int m = 1; m <= 2; m <<= 1) {
                uint64_t p0 = __shfl_xor((unsigned long long)m0, m, 64);
                uint64_t p1 = __shfl_xor((unsigned long long)m1, m, 64);
                uint64_t p2 = __shfl_xor((unsigned long long)m2, m, 64);
                insert3(p0, m0, m1, m2);
                insert3(p1, m0, m1, m2);
                insert3(p2, m0, m1, m2);
            }
            float bound = ((r - 1) * h) * ((r - 1) * h) * 0.99999f;
            float d2cur = __uint_as_float((uint32_t)(m2 >> 32)); // NaN if unset -> no stop
            if (d2cur < bound || r >= G_GRID) break;
        }
        int x0 = max(cx - r, 0), x1 = min(cx + r, G_GRID - 1);
        int y0 = max(cy - r, 0), y1 = min(cy + r, G_GRID - 1);
        int cidx = 0;
        for (int yy = y0; yy <= y1; yy++) {
            bool yedge = (yy == cy - r) || (yy == cy + r);
            for (int xx = x0; xx <= x1; xx++) {
                if (r > 0 && !yedge && xx != cx - r && xx != cx + r) continue;
                if ((cidx++ & 3) != sub) continue;
                int c = yy * G_GRID + xx;
                int p0 = cellstart[c], p1 = cellstart[c + 1];
                for (int p = p0; p < p1; p++) {
                    float2 sp = spos[p];
                    float ddx = __fadd_rn(sp.x, -tx);
                    float ddy = __fadd_rn(sp.y, -ty);
                    float dd = __fadd_rn(__fmul_rn(ddx, ddx), __fmul_rn(ddy, ddy));
                    uint64_t key = ((uint64_t)__float_as_uint(dd) << 32) | (uint32_t)sidx[p];
                    insert3(key, k0, k1, k2);
                }
            }
        }
    }

    if (sub == 0) {
        float d0 = __uint_as_float((uint32_t)(m0 >> 32));
        float d1 = __uint_as_float((uint32_t)(m1 >> 32));
        float d2 = __uint_as_float((uint32_t)(m2 >> 32));
        float w0 = 1.0f / fmaxf(d0, 1e-16f);
        float w1 = 1.0f / fmaxf(d1, 1e-16f);
        float w2 = 1.0f / fmaxf(d2, 1e-16f);
        float wsum = w0 + w1 + w2;
        knn_idx[t*3+0] = (int)(uint32_t)m0;
        knn_idx[t*3+1] = (int)(uint32_t)m1;
        knn_idx[t*3+2] = (int)(uint32_t)m2;
        knn_w[t*3+0] = w0 / wsum;
        knn_w[t*3+1] = w1 / wsum;
        knn_w[t*3+2] = w2 / wsum;
    }
}

// ---------- kernel 8: weighted gather, one wave per target ----------
__global__ __launch_bounds__(256) void gather_kernel(const float* __restrict__ h2,
    const int* __restrict__ knn_idx, const float* __restrict__ knn_w,
    float* __restrict__ out)
{
    int m = blockIdx.x * 4 + (threadIdx.x >> 6);
    int lane = threadIdx.x & 63;
    const float2* h2v = (const float2*)h2;
    int j0 = knn_idx[m*3+0], j1 = knn_idx[m*3+1], j2 = knn_idx[m*3+2];
    float w0 = knn_w[m*3+0], w1 = knn_w[m*3+1], w2 = knn_w[m*3+2];
    float2 a = h2v[j0*64 + lane], b = h2v[j1*64 + lane], c = h2v[j2*64 + lane];
    float2 v;
    v.x = w0*a.x + w1*b.x + w2*c.x;
    v.y = w0*a.y + w1*b.y + w2*c.y;
    ((float2*)out)[m*64 + lane] = v;
}

extern "C" void kernel_launch(void* const* d_in, const int* in_sizes, int n_in,
                              void* d_out, int out_size, void* d_ws, size_t ws_size,
                              hipStream_t stream) {
    const float* x        = (const float*)d_in[0];
    const float* pos      = (const float*)d_in[1];
    const float* pos_skip = (const float*)d_in[2];
    const int*   ei       = (const int*)  d_in[3];
    const float* Wc       = (const float*)d_in[4];
    const float* bc       = (const float*)d_in[5];
    const float* W2       = (const float*)d_in[6];
    const float* b2       = (const float*)d_in[7];
    float* out = (float*)d_out;

    char* ws = (char*)d_ws;
    size_t off = 0;
    auto alloc = [&](size_t bytes) {
        void* p = ws + off;
        off = (off + bytes + 255) & ~(size_t)255;
        return p;
    };
    int*    cnt        = (int*)   alloc((size_t)N_NODES * 4);
    int*    cellcnt    = (int*)   alloc((size_t)N_CELLS * 4);
    int*    cursor     = (int*)   alloc((size_t)N_NODES * 4);
    int*    rowstart   = (int*)   alloc((size_t)(N_NODES + 1) * 4);
    int*    cellcursor = (int*)   alloc((size_t)N_CELLS * 4);
    int*    cellstart  = (int*)   alloc((size_t)(N_CELLS + 1) * 4);
    int*    esrc       = (int*)   alloc((size_t)E_EDGES * 4);
    float*  edx        = (float*) alloc((size_t)E_EDGES * 4);
    float*  edy        = (float*) alloc((size_t)E_EDGES * 4);
    float2* spos       = (float2*)alloc((size_t)N_NODES * 8);
    int*    sidx       = (int*)   alloc((size_t)N_NODES * 4);
    float*  h2         = (float*) alloc((size_t)N_NODES * F_CH * 4);
    int*    knn_idx    = (int*)   alloc((size_t)M_PTS * 3 * 4);
    float*  knn_w      = (float*) alloc((size_t)M_PTS * 3 * 4);
    ushort* Wct_h      = (ushort*)alloc((size_t)F_CH * 512 * 2);
    ushort* Wct_l      = (ushort*)alloc((size_t)F_CH * 512 * 2);
    ushort* W2t_h      = (ushort*)alloc((size_t)F_CH * 128 * 2);
    ushort* W2t_l      = (ushort*)alloc((size_t)F_CH * 128 * 2);
    ushort* aggA_h     = (ushort*)alloc((size_t)N_NODES * 512 * 2);
    ushort* aggA_l     = (ushort*)alloc((size_t)N_NODES * 512 * 2);

    hipMemsetAsync(cnt, 0, (size_t)N_NODES * 4, stream);
    hipMemsetAsync(cellcnt, 0, (size_t)N_CELLS * 4, stream);
    const int TOT = E_EDGES + N_NODES;
    count_all_kernel<<<(TOT + 255) / 256, 256, 0, stream>>>(ei, pos, cnt, cellcnt);
    scan_both_kernel<<<2, 1024, 0, stream>>>(cnt, rowstart, cursor, cellcnt, cellstart, cellcursor);
    scatter_all_kernel<<<(TOT + 255) / 256, 256, 0, stream>>>(ei, pos, cursor, esrc, edx, edy,
                                                              cellcursor, spos, sidx);
    prep_w_kernel<<<(4*C_CH*F_CH + F_CH*F_CH + 255) / 256, 256, 0, stream>>>(
        Wc, W2, Wct_h, Wct_l, W2t_h, W2t_l);
    agg_kernel<<<N_NODES / 4, 256, 0, stream>>>(x, rowstart, esrc, edx, edy, aggA_h, aggA_l);
    gemm_kernel<<<N_NODES / NPB, 128, 0, stream>>>(aggA_h, aggA_l,
        Wct_h, Wct_l, W2t_h, W2t_l, bc, b2, h2);
    knn_grid_kernel<<<(M_PTS*4 + 255) / 256, 256, 0, stream>>>(pos_skip, cellstart, spos, sidx, knn_idx, knn_w);
    gather_kernel<<<M_PTS / 4, 256, 0, stream>>>(h2, knn_idx, knn_w, out);
}

// Round 6
// 178.958 us; speedup vs baseline: 1.9571x; 1.1115x over previous
//
#include <hip/hip_runtime.h>
#include <hip/hip_bf16.h>
#include <math.h>
#include <float.h>
#include <stdint.h>

#define N_NODES 10000
#define M_PTS   20000
#define E_EDGES 160000
#define C_CH    128
#define F_CH    128
#define G_GRID  64
#define N_CELLS (G_GRID*G_GRID)
#define NPB     16      // nodes per block in gemm kernel (one 16-row MFMA tile)
#define ECAP    64      // max edges stored per node   (Pois(16):  P(>64) ~ 1e-18)
#define CCAP    24      // max points stored per cell  (Pois(2.44): P(>24) ~ 1e-13)

typedef __attribute__((ext_vector_type(8))) short short8;
typedef __attribute__((ext_vector_type(4))) float f32x4;

__device__ inline ushort f2bf(float v) {
    __hip_bfloat16 b = __float2bfloat16(v);
    return *reinterpret_cast<ushort*>(&b);
}
__device__ inline float bf2f(ushort u) {
    __hip_bfloat16 b = *reinterpret_cast<__hip_bfloat16*>(&u);
    return __bfloat162float(b);
}
__device__ inline float eluf(float v) { return (v > 0.f) ? v : expm1f(v); }

// ---------- kernel 1: build edge buckets + cell buckets + W transposes, one pass ----------
// thread ranges: [0,E) edges | [E,E+N) points | then Wc (4C*F) | then W2 (F*F)
__global__ __launch_bounds__(256) void build_kernel(const int* __restrict__ ei,
    const float* __restrict__ pos,
    int* __restrict__ ecur, int* __restrict__ ccur,
    int4* __restrict__ edata, int4* __restrict__ cdata,
    const float* __restrict__ Wc, const float* __restrict__ W2,
    ushort* __restrict__ Wct_h, ushort* __restrict__ Wct_l,
    ushort* __restrict__ W2t_h, ushort* __restrict__ W2t_l)
{
    int i = blockIdx.x * blockDim.x + threadIdx.x;
    if (i < E_EDGES) {
        int src = ei[i];
        int dst = ei[E_EDGES + i];
        float dxv = pos[2*dst]     - pos[2*src];
        float dyv = pos[2*dst + 1] - pos[2*src + 1];
        float r2 = dxv*dxv + dyv*dyv;
        float scale = 1.0f / (r2 + 0.01f);
        int slot = atomicAdd(&ecur[dst], 1);
        if (slot < ECAP)
            edata[dst*ECAP + slot] = make_int4(src, __float_as_int(dxv*scale),
                                               __float_as_int(dyv*scale), 0);
    } else if (i < E_EDGES + N_NODES) {
        int j = i - E_EDGES;
        float px = pos[2*j], py = pos[2*j+1];
        int cx = min(max((int)(px * G_GRID), 0), G_GRID - 1);
        int cy = min(max((int)(py * G_GRID), 0), G_GRID - 1);
        int c = cy * G_GRID + cx;
        int slot = atomicAdd(&ccur[c], 1);
        if (slot < CCAP)
            cdata[c*CCAP + slot] = make_int4(__float_as_int(px), __float_as_int(py), j, 0);
    } else if (i < E_EDGES + N_NODES + 4*C_CH*F_CH) {
        int j = i - (E_EDGES + N_NODES);
        int k = j >> 7, n = j & 127;      // Wc[k][n]
        float v = Wc[j];
        ushort h = f2bf(v);
        ushort l = f2bf(v - bf2f(h));
        Wct_h[n*512 + k] = h;
        Wct_l[n*512 + k] = l;
    } else if (i < E_EDGES + N_NODES + 4*C_CH*F_CH + F_CH*F_CH) {
        int j = i - (E_EDGES + N_NODES + 4*C_CH*F_CH);
        int k = j >> 7, n = j & 127;      // W2[k][n]
        float v = W2[j];
        ushort h = f2bf(v);
        ushort l = f2bf(v - bf2f(h));
        W2t_h[n*128 + k] = h;
        W2t_l[n*128 + k] = l;
    }
}

// ---------- kernel 2: aggregation, one wave per node ----------
// Writes A row [agg_dx(128) | agg_dy(128) | agg_mean(128) | x(128)] as bf16 hi/lo planes.
__global__ __launch_bounds__(256) void agg_kernel(const float* __restrict__ x,
    const int* __restrict__ ecur, const int4* __restrict__ edata,
    ushort* __restrict__ aggA_h, ushort* __restrict__ aggA_l)
{
    int node = blockIdx.x * 4 + (threadIdx.x >> 6);
    int lane = threadIdx.x & 63;
    const float2* xv = (const float2*)x;
    float2 xi = xv[(size_t)node*64 + lane];
    int cnt = ecur[node];
    int m = min(cnt, ECAP);
    const int4* eb = edata + node*ECAP;
    float a1x = 0.f, a1y = 0.f, a2x = 0.f, a2y = 0.f, a3x = 0.f, a3y = 0.f;
    int p = 0;
    for (; p + 3 < m; p += 4) {
        int4 e0 = eb[p], e1 = eb[p+1], e2 = eb[p+2], e3 = eb[p+3];
        float2 x0 = xv[(size_t)e0.x*64 + lane];
        float2 x1 = xv[(size_t)e1.x*64 + lane];
        float2 x2 = xv[(size_t)e2.x*64 + lane];
        float2 x3 = xv[(size_t)e3.x*64 + lane];
        float dx0 = __int_as_float(e0.y), dy0 = __int_as_float(e0.z);
        float dx1 = __int_as_float(e1.y), dy1 = __int_as_float(e1.z);
        float dx2 = __int_as_float(e2.y), dy2 = __int_as_float(e2.z);
        float dx3 = __int_as_float(e3.y), dy3 = __int_as_float(e3.z);
        a1x = fmaf(xi.x - x0.x, dx0, a1x); a1y = fmaf(xi.y - x0.y, dx0, a1y);
        a2x = fmaf(xi.x - x0.x, dy0, a2x); a2y = fmaf(xi.y - x0.y, dy0, a2y);
        a3x += x0.x; a3y += x0.y;
        a1x = fmaf(xi.x - x1.x, dx1, a1x); a1y = fmaf(xi.y - x1.y, dx1, a1y);
        a2x = fmaf(xi.x - x1.x, dy1, a2x); a2y = fmaf(xi.y - x1.y, dy1, a2y);
        a3x += x1.x; a3y += x1.y;
        a1x = fmaf(xi.x - x2.x, dx2, a1x); a1y = fmaf(xi.y - x2.y, dx2, a1y);
        a2x = fmaf(xi.x - x2.x, dy2, a2x); a2y = fmaf(xi.y - x2.y, dy2, a2y);
        a3x += x2.x; a3y += x2.y;
        a1x = fmaf(xi.x - x3.x, dx3, a1x); a1y = fmaf(xi.y - x3.y, dx3, a1y);
        a2x = fmaf(xi.x - x3.x, dy3, a2x); a2y = fmaf(xi.y - x3.y, dy3, a2y);
        a3x += x3.x; a3y += x3.y;
    }
    for (; p < m; p++) {
        int4 e = eb[p];
        float2 xj = xv[(size_t)e.x*64 + lane];
        float dxe = __int_as_float(e.y), dye = __int_as_float(e.z);
        a1x = fmaf(xi.x - xj.x, dxe, a1x); a1y = fmaf(xi.y - xj.y, dxe, a1y);
        a2x = fmaf(xi.x - xj.x, dye, a2x); a2y = fmaf(xi.y - xj.y, dye, a2y);
        a3x += xj.x; a3y += xj.y;
    }
    float inv = 1.0f / fmaxf((float)cnt, 1.0f);
    float vals[4][2] = {{a1x*inv, a1y*inv}, {a2x*inv, a2y*inv}, {a3x*inv, a3y*inv}, {xi.x, xi.y}};
    size_t rb = (size_t)node * 512;
    int c0 = 2*lane;
    #pragma unroll
    for (int seg = 0; seg < 4; seg++) {
        ushort hx = f2bf(vals[seg][0]), hy = f2bf(vals[seg][1]);
        ushort lx = f2bf(vals[seg][0] - bf2f(hx)), ly = f2bf(vals[seg][1] - bf2f(hy));
        *(uint*)&aggA_h[rb + seg*128 + c0] = (uint)hx | ((uint)hy << 16);
        *(uint*)&aggA_l[rb + seg*128 + c0] = (uint)lx | ((uint)ly << 16);
    }
}

// ---------- kernel 3: MFMA GEMM1 + ELU + MFMA GEMM2 + ELU ----------
// A fragments read straight from L2-resident aggA (no LDS staging, no barrier).
#define H_STRIDE 136   // ushorts per row: 128 + 8 pad
__global__ __launch_bounds__(128) void gemm_kernel(
    const ushort* __restrict__ aggA_h, const ushort* __restrict__ aggA_l,
    const ushort* __restrict__ Wct_h, const ushort* __restrict__ Wct_l,
    const ushort* __restrict__ W2t_h, const ushort* __restrict__ W2t_l,
    const float* __restrict__ bc, const float* __restrict__ b2,
    float* __restrict__ h2out)
{
    __shared__ alignas(16) ushort sH_h[NPB * H_STRIDE];
    __shared__ alignas(16) ushort sH_l[NPB * H_STRIDE];

    const int tid = threadIdx.x;
    const int nodeBase = blockIdx.x * NPB;
    const int lane = tid & 63;
    const int wave = tid >> 6;
    const int col16 = lane & 15;
    const int quad  = lane >> 4;
    const int row = col16;

    f32x4 acc[4] = {f32x4{0,0,0,0}, f32x4{0,0,0,0}, f32x4{0,0,0,0}, f32x4{0,0,0,0}};
    int ncol[4]; float bcv[4], b2v[4];
    #pragma unroll
    for (int nt = 0; nt < 4; nt++) {
        ncol[nt] = wave*64 + nt*16 + col16;
        bcv[nt] = bc[ncol[nt]];
        b2v[nt] = b2[ncol[nt]];
    }
    const size_t arow = (size_t)(nodeBase + row) * 512;
    for (int ks = 0; ks < 16; ks++) {
        int kb = ks*32 + quad*8;
        short8 ah = *(const short8*)(aggA_h + arow + kb);
        short8 al = *(const short8*)(aggA_l + arow + kb);
        #pragma unroll
        for (int nt = 0; nt < 4; nt++) {
            short8 bh = *(const short8*)(Wct_h + (size_t)ncol[nt]*512 + kb);
            short8 bl = *(const short8*)(Wct_l + (size_t)ncol[nt]*512 + kb);
            acc[nt] = __builtin_amdgcn_mfma_f32_16x16x32_bf16(ah, bh, acc[nt], 0, 0, 0);
            acc[nt] = __builtin_amdgcn_mfma_f32_16x16x32_bf16(ah, bl, acc[nt], 0, 0, 0);
            acc[nt] = __builtin_amdgcn_mfma_f32_16x16x32_bf16(al, bh, acc[nt], 0, 0, 0);
        }
    }

    #pragma unroll
    for (int nt = 0; nt < 4; nt++) {
        #pragma unroll
        for (int r = 0; r < 4; r++) {
            int rr = quad*4 + r;
            float v = eluf(acc[nt][r] + bcv[nt]);
            ushort hh = f2bf(v);
            sH_h[rr*H_STRIDE + ncol[nt]] = hh;
            sH_l[rr*H_STRIDE + ncol[nt]] = f2bf(v - bf2f(hh));
        }
    }
    __syncthreads();

    f32x4 acc2[4] = {f32x4{0,0,0,0}, f32x4{0,0,0,0}, f32x4{0,0,0,0}, f32x4{0,0,0,0}};
    for (int ks = 0; ks < 4; ks++) {
        int kb = ks*32 + quad*8;
        short8 ah = *(const short8*)&sH_h[row*H_STRIDE + kb];
        short8 al = *(const short8*)&sH_l[row*H_STRIDE + kb];
        #pragma unroll
        for (int nt = 0; nt < 4; nt++) {
            short8 bh = *(const short8*)(W2t_h + ncol[nt]*128 + kb);
            short8 bl = *(const short8*)(W2t_l + ncol[nt]*128 + kb);
            acc2[nt] = __builtin_amdgcn_mfma_f32_16x16x32_bf16(ah, bh, acc2[nt], 0, 0, 0);
            acc2[nt] = __builtin_amdgcn_mfma_f32_16x16x32_bf16(ah, bl, acc2[nt], 0, 0, 0);
            acc2[nt] = __builtin_amdgcn_mfma_f32_16x16x32_bf16(al, bh, acc2[nt], 0, 0, 0);
        }
    }

    #pragma unroll
    for (int nt = 0; nt < 4; nt++) {
        #pragma unroll
        for (int r = 0; r < 4; r++) {
            int node = nodeBase + quad*4 + r;
            float v = eluf(acc2[nt][r] + b2v[nt]);
            h2out[(size_t)node*F_CH + ncol[nt]] = v;
        }
    }
}

// ---------- kernel 4: grid 3-NN (4 sub-lanes/target) + fused weighted gather ----------
// Cell scan ownership is disjoint across sub-lanes; stop-test merges go into
// temporaries only (disjoint sets at each butterfly step -> no duplicates).
__device__ inline void insert3(uint64_t key, uint64_t& k0, uint64_t& k1, uint64_t& k2) {
    bool lt2 = key < k2, lt1 = key < k1, lt0 = key < k0;
    k2 = lt1 ? k1 : (lt2 ? key : k2);
    k1 = lt0 ? k0 : (lt1 ? key : k1);
    k0 = lt0 ? key : k0;
}
__global__ __launch_bounds__(256) void knn_gather_kernel(const float* __restrict__ pos_skip,
    const int* __restrict__ ccur, const int4* __restrict__ cdata,
    const float* __restrict__ h2, float* __restrict__ out)
{
    int gt = blockIdx.x * blockDim.x + threadIdx.x;
    int t = gt >> 2;
    int sub = gt & 3;
    if (t >= M_PTS) return;
    float tx = pos_skip[2*t], ty = pos_skip[2*t+1];
    const float h = 1.0f / G_GRID;
    int cx = min(max((int)(tx * G_GRID), 0), G_GRID - 1);
    int cy = min(max((int)(ty * G_GRID), 0), G_GRID - 1);

    uint64_t k0 = UINT64_MAX, k1 = UINT64_MAX, k2 = UINT64_MAX;   // own candidates only
    uint64_t m0 = UINT64_MAX, m1 = UINT64_MAX, m2 = UINT64_MAX;   // merged (final answer)

    for (int r = 0; ; r++) {
        if (r > 0) {
            m0 = k0; m1 = k1; m2 = k2;
            #pragma unroll
            for (int m = 1; m <= 2; m <<= 1) {
                uint64_t p0 = __shfl_xor((unsigned long long)m0, m, 64);
                uint64_t p1 = __shfl_xor((unsigned long long)m1, m, 64);
                uint64_t p2 = __shfl_xor((unsigned long long)m2, m, 64);
                insert3(p0, m0, m1, m2);
                insert3(p1, m0, m1, m2);
                insert3(p2, m0, m1, m2);
            }
            float bound = ((r - 1) * h) * ((r - 1) * h) * 0.99999f;
            float d2cur = __uint_as_float((uint32_t)(m2 >> 32)); // NaN if unset -> no stop
            if (d2cur < bound || r >= G_GRID) break;
        }
        int x0 = max(cx - r, 0), x1 = min(cx + r, G_GRID - 1);
        int y0 = max(cy - r, 0), y1 = min(cy + r, G_GRID - 1);
        int cidx = 0;
        for (int yy = y0; yy <= y1; yy++) {
            bool yedge = (yy == cy - r) || (yy == cy + r);
            for (int xx = x0; xx <= x1; xx++) {
                if (r > 0 && !yedge && xx != cx - r && xx != cx + r) continue;
                if ((cidx++ & 3) != sub) continue;
                int c = yy * G_GRID + xx;
                int pc = min(ccur[c], CCAP);
                const int4* cb = cdata + c*CCAP;
                for (int p = 0; p < pc; p++) {
                    int4 sp = cb[p];
                    float ddx = __fadd_rn(__int_as_float(sp.x), -tx);
                    float ddy = __fadd_rn(__int_as_float(sp.y), -ty);
                    float dd = __fadd_rn(__fmul_rn(ddx, ddx), __fmul_rn(ddy, ddy));
                    uint64_t key = ((uint64_t)__float_as_uint(dd) << 32) | (uint32_t)sp.z;
                    insert3(key, k0, k1, k2);
                }
            }
        }
    }

    // fused gather: all 4 sub-lanes hold identical merged m0..m2
    float d0 = __uint_as_float((uint32_t)(m0 >> 32));
    float d1 = __uint_as_float((uint32_t)(m1 >> 32));
    float d2 = __uint_as_float((uint32_t)(m2 >> 32));
    float w0 = 1.0f / fmaxf(d0, 1e-16f);
    float w1 = 1.0f / fmaxf(d1, 1e-16f);
    float w2 = 1.0f / fmaxf(d2, 1e-16f);
    float wsum = w0 + w1 + w2;
    w0 /= wsum; w1 /= wsum; w2 /= wsum;
    int j0 = (int)(uint32_t)m0, j1 = (int)(uint32_t)m1, j2 = (int)(uint32_t)m2;
    const float4* r0 = (const float4*)(h2 + (size_t)j0*F_CH);
    const float4* r1 = (const float4*)(h2 + (size_t)j1*F_CH);
    const float4* r2 = (const float4*)(h2 + (size_t)j2*F_CH);
    float4* ot = (float4*)(out + (size_t)t*F_CH);
    #pragma unroll
    for (int q = 0; q < 8; q++) {
        int idx = sub*8 + q;
        float4 a = r0[idx], b = r1[idx], c = r2[idx];
        float4 v;
        v.x = w0*a.x + w1*b.x + w2*c.x;
        v.y = w0*a.y + w1*b.y + w2*c.y;
        v.z = w0*a.z + w1*b.z + w2*c.z;
        v.w = w0*a.w + w1*b.w + w2*c.w;
        ot[idx] = v;
    }
}

extern "C" void kernel_launch(void* const* d_in, const int* in_sizes, int n_in,
                              void* d_out, int out_size, void* d_ws, size_t ws_size,
                              hipStream_t stream) {
    const float* x        = (const float*)d_in[0];
    const float* pos      = (const float*)d_in[1];
    const float* pos_skip = (const float*)d_in[2];
    const int*   ei       = (const int*)  d_in[3];
    const float* Wc       = (const float*)d_in[4];
    const float* bc       = (const float*)d_in[5];
    const float* W2       = (const float*)d_in[6];
    const float* b2       = (const float*)d_in[7];
    float* out = (float*)d_out;

    char* ws = (char*)d_ws;
    size_t off = 0;
    auto alloc = [&](size_t bytes) {
        void* p = ws + off;
        off = (off + bytes + 255) & ~(size_t)255;
        return p;
    };
    // cursors first & adjacent: one memset covers both
    int*    ecur   = (int*)   alloc((size_t)N_NODES * 4);
    int*    ccur   = (int*)   alloc((size_t)N_CELLS * 4);
    size_t  cur_bytes = (size_t)((char*)ccur - (char*)ecur) + (size_t)N_CELLS * 4;
    int4*   edata  = (int4*)  alloc((size_t)N_NODES * ECAP * 16);
    int4*   cdata  = (int4*)  alloc((size_t)N_CELLS * CCAP * 16);
    float*  h2     = (float*) alloc((size_t)N_NODES * F_CH * 4);
    ushort* Wct_h  = (ushort*)alloc((size_t)F_CH * 512 * 2);
    ushort* Wct_l  = (ushort*)alloc((size_t)F_CH * 512 * 2);
    ushort* W2t_h  = (ushort*)alloc((size_t)F_CH * 128 * 2);
    ushort* W2t_l  = (ushort*)alloc((size_t)F_CH * 128 * 2);
    ushort* aggA_h = (ushort*)alloc((size_t)N_NODES * 512 * 2);
    ushort* aggA_l = (ushort*)alloc((size_t)N_NODES * 512 * 2);

    hipMemsetAsync(ecur, 0, cur_bytes, stream);
    const int TOT_ALL = E_EDGES + N_NODES + 4*C_CH*F_CH + F_CH*F_CH;
    build_kernel<<<(TOT_ALL + 255) / 256, 256, 0, stream>>>(ei, pos, ecur, ccur, edata, cdata,
                                                            Wc, W2, Wct_h, Wct_l, W2t_h, W2t_l);
    agg_kernel<<<N_NODES / 4, 256, 0, stream>>>(x, ecur, edata, aggA_h, aggA_l);
    gemm_kernel<<<N_NODES / NPB, 128, 0, stream>>>(aggA_h, aggA_l,
        Wct_h, Wct_l, W2t_h, W2t_l, bc, b2, h2);
    knn_gather_kernel<<<(M_PTS*4 + 255) / 256, 256, 0, stream>>>(pos_skip, ccur, cdata, h2, out);
}